// Round 1
// 219.407 us; speedup vs baseline: 1.0339x; 1.0339x over previous
//
#include <hip/hip_runtime.h>
#include <hip/hip_bf16.h>

// ---------------------------------------------------------------------------
// Fused: h = rmsnorm(x@W0+b0); h = sigmoid(h@W1+b1)+h; out = relu(h@W2+b2)+h
// M=32768, D=1024, H=128.  fp32 in / fp32 out, bf16 MFMA with fp32 accum.
//
// R8: latency-bound fix (fused was 77.6us @ 1.1TB/s, occ 21%, all pipes idle):
//  - M-tile 128 -> 64: grid 256 -> 512 = 2 blocks/CU (LDS 48KB/block,
//    __launch_bounds__(512,4) keeps VGPR<=128 so 16 waves/CU resident).
//  - depth-2 register prefetch holding RAW fp32 (convert at LDS-write time,
//    not load time -- R7 converted inside preload which forced a vmcnt wait
//    at issue and serialized every slab on HBM latency).
//  - double-buffered GEMM0 LDS slabs, ONE barrier per slab (was 2).
//    WAR hazard on buf[s&1] is covered by the barrier at slab s-1.
//  Numerics identical to R7 (same K order, rounding, swizzles).
// ---------------------------------------------------------------------------

using u16    = unsigned short;
using f32x4  = __attribute__((ext_vector_type(4))) float;
using bf16x8 = __attribute__((ext_vector_type(8))) short;   // 8 bf16 = 4 VGPRs
using u16x8  = __attribute__((ext_vector_type(8))) unsigned short;

__device__ __forceinline__ float bf2f(u16 u) {
  union { unsigned int i; float f; } v; v.i = ((unsigned int)u) << 16; return v.f;
}
__device__ __forceinline__ u16 f2bf(float f) {
  union { float f; unsigned int i; } v; v.f = f;
  unsigned int r = v.i + 0x7fffu + ((v.i >> 16) & 1u);   // RNE
  return (u16)(r >> 16);
}

// ws layout (byte offsets): [0,64) unused; W0T bf16[128][1024] @64;
// W1T bf16[128][128] @262208; W2T @294976; biases fp32[3][128] @327744.
#define WS_W0T 64
#define WS_W1T 262208
#define WS_W2T 294976
#define WS_BIAS 327744

// swizzled byte offset into [rows][16 chunks of 8 bf16] tile (256B/row)
__device__ __forceinline__ int hoff(int row, int col) {
  return row * 256 + (((col >> 3) ^ (row & 7)) << 4) + ((col & 7) << 1);
}

// ---------------------------------------------------------------------------
// prep: W0(1024x128) fp32 -> W0T bf16; W1/W2(128x128) fp32 -> W1T/W2T bf16;
// biases fp32 -> fp32. blocks 0..127 W0, 128..143 W1, 144..159 W2, 160 biases.
// (unchanged from R7)
// ---------------------------------------------------------------------------
__global__ void __launch_bounds__(256)
prep_kernel(const float* __restrict__ W0, const float* __restrict__ W1,
            const float* __restrict__ W2, const float* __restrict__ b0,
            const float* __restrict__ b1, const float* __restrict__ b2,
            char* __restrict__ wsb) {
  const int bid = blockIdx.x;
  if (bid == 160) {
    float* bias = (float*)(wsb + WS_BIAS);
    for (int i = threadIdx.x; i < 384; i += 256) {
      int which = i >> 7, j = i & 127;
      const float* src = (which == 0) ? b0 : (which == 1) ? b1 : b2;
      bias[i] = src[j];
    }
    return;
  }
  __shared__ float tile[32][33];
  const float* src; u16* dst; int K, N, kt, nt;
  if (bid < 128)      { src = W0; dst = (u16*)(wsb + WS_W0T); K = 1024; N = 128; kt = bid >> 2;         nt = bid & 3; }
  else if (bid < 144) { src = W1; dst = (u16*)(wsb + WS_W1T); K = 128;  N = 128; kt = (bid - 128) >> 2; nt = (bid - 128) & 3; }
  else                { src = W2; dst = (u16*)(wsb + WS_W2T); K = 128;  N = 128; kt = (bid - 144) >> 2; nt = (bid - 144) & 3; }
  const int tx = threadIdx.x & 31, ty = threadIdx.x >> 5;
#pragma unroll
  for (int i = 0; i < 4; ++i) {
    int k = kt * 32 + ty + i * 8, n = nt * 32 + tx;
    tile[ty + i * 8][tx] = src[(size_t)k * N + n];
  }
  __syncthreads();
#pragma unroll
  for (int i = 0; i < 4; ++i) {
    int n = nt * 32 + ty + i * 8, k = kt * 32 + tx;
    dst[(size_t)n * K + k] = f2bf(tile[tx][ty + i * 8]);
  }
}

// ---------------------------------------------------------------------------
// fused kernel — M-tile 64, 512 threads (8 waves: 2 M-waves x 4 N-waves),
// grid 512 (2 blocks/CU). Depth-2 raw-fp32 prefetch + double-buffered LDS.
// LDS: buf0 = xs@0 (8K) + ws@8192 (16K); buf1 = xs@24576 + ws@32768.
// After GEMM0: hns@0 (16K, [64][256B] swizzled), h1s@16384 (16K).
// ---------------------------------------------------------------------------
__global__ void __launch_bounds__(512, 4)
fused_kernel(const float* __restrict__ xin, const char* __restrict__ wsb,
             float* __restrict__ outv) {
  __shared__ char smem[49152];
  char* hns = smem;           // after GEMM0: [64][128] bf16 swizzled, 16KB
  char* h1s = smem + 16384;   // 16KB

  const u16* w0t    = (const u16*)(wsb + WS_W0T);
  const u16* w1t    = (const u16*)(wsb + WS_W1T);
  const u16* w2t    = (const u16*)(wsb + WS_W2T);
  const float* bias = (const float*)(wsb + WS_BIAS);

  const int tid    = threadIdx.x;
  const int lane   = tid & 63;
  const int wave   = tid >> 6;
  const int lane16 = lane & 15;
  const int quad   = lane >> 4;
  const int m_base = (wave & 1) * 32;     // 2 M-waves cover 64 rows
  const int n_base = (wave >> 1) * 32;    // 4 N-waves cover 128 cols
  const int row0   = blockIdx.x * 64;

  // staging assignment: x-slab 64 rows x 8 chunks -> 1 chunk/thread;
  // w-slab 128 rows x 8 chunks -> 2 chunks/thread (rows rx and rx+64).
  const int rx  = tid >> 3;               // 0..63
  const int cx  = tid & 7;
  const int xsw = (cx ^ (rx & 7)) << 4;   // swizzled chunk offset (rx+64 same)

  // depth-2 prefetch buffers: raw fp32 x (convert at write time) + bf16 w
  f32x4 xA0, xA1, xB0, xB1;
  u16x8 wA0, wA1, wB0, wB1;

  auto preload = [&](f32x4& x0, f32x4& x1, u16x8& w0, u16x8& w1, int k0) {
    const float* p = xin + (size_t)(row0 + rx) * 1024 + k0 + cx * 8;
    x0 = *(const f32x4*)p;
    x1 = *(const f32x4*)(p + 4);
    const u16* wp = w0t + (size_t)rx * 1024 + k0 + cx * 8;
    w0 = *(const u16x8*)wp;
    w1 = *(const u16x8*)(wp + 65536);     // +64 rows * 1024
  };

  auto stage = [&](char* xs, char* wsm, const f32x4& x0, const f32x4& x1,
                   const u16x8& w0, const u16x8& w1) {
    u16x8 t;
#pragma unroll
    for (int e = 0; e < 4; ++e) { t[e] = f2bf(x0[e]); t[e + 4] = f2bf(x1[e]); }
    *(u16x8*)(xs + rx * 128 + xsw) = t;
    *(u16x8*)(wsm + rx * 128 + xsw) = w0;
    *(u16x8*)(wsm + (rx + 64) * 128 + xsw) = w1;
  };

  f32x4 acc[2][2] = {};

  auto mmac = [&](const char* xs, const char* wsm) {
#pragma unroll
    for (int kk = 0; kk < 2; ++kk) {
      int ph = ((kk * 4 + quad) ^ (lane & 7)) << 4;
      bf16x8 a[2], b[2];
#pragma unroll
      for (int rh = 0; rh < 2; ++rh)
        a[rh] = *(const bf16x8*)(xs + (m_base + rh * 16 + lane16) * 128 + ph);
#pragma unroll
      for (int nt = 0; nt < 2; ++nt)
        b[nt] = *(const bf16x8*)(wsm + (n_base + nt * 16 + lane16) * 128 + ph);
#pragma unroll
      for (int rh = 0; rh < 2; ++rh)
#pragma unroll
        for (int nt = 0; nt < 2; ++nt)
          acc[rh][nt] = __builtin_amdgcn_mfma_f32_16x16x32_bf16(
              a[rh], b[nt], acc[rh][nt], 0, 0, 0);
    }
  };

  float b0v[2];
#pragma unroll
  for (int nt = 0; nt < 2; ++nt) b0v[nt] = bias[n_base + nt * 16 + lane16];

  preload(xA0, xA1, wA0, wA1, 0);
  preload(xB0, xB1, wB0, wB1, 64);

  // ---- GEMM0: h = x @ W0, K=1024, 16 slabs of BK=64, double-buffered.
  // One barrier per slab: write buf[s&1] (last read at slab s-2, barrier at
  // s-1 intervenes), barrier, MFMA. A/B unrolled so no reg-copy waits.
  for (int ss = 0; ss < 8; ++ss) {
    const int s0 = ss * 2;
    stage(smem, smem + 8192, xA0, xA1, wA0, wA1);
    if (s0 + 2 < 16) preload(xA0, xA1, wA0, wA1, (s0 + 2) * 64);
    __syncthreads();
    mmac(smem, smem + 8192);

    stage(smem + 24576, smem + 32768, xB0, xB1, wB0, wB1);
    if (s0 + 3 < 16) preload(xB0, xB1, wB0, wB1, (s0 + 3) * 64);
    __syncthreads();
    mmac(smem + 24576, smem + 32768);
  }
  // no barrier needed: scatter targets [0,16K); stragglers only read buf1
  // [24576,49152) (disjoint); own buf0 reads retired before last barrier.

  // ---- scatter h+b0 -> hns (C-layout: col=lane16, row=quad*4+reg) ----
#pragma unroll
  for (int rh = 0; rh < 2; ++rh)
#pragma unroll
    for (int nt = 0; nt < 2; ++nt) {
      int col = n_base + nt * 16 + lane16;
#pragma unroll
      for (int r = 0; r < 4; ++r) {
        int row = m_base + rh * 16 + quad * 4 + r;
        *(u16*)(hns + hoff(row, col)) = f2bf(acc[rh][nt][r] + b0v[nt]);
      }
    }
  __syncthreads();

  // ---- rmsnorm over H=128: 8 threads/row, 2 chunks each ----
  {
    int r = tid >> 3, q = tid & 7;
    u16x8 vals[2];
    float sum = 0.f;
#pragma unroll
    for (int j = 0; j < 2; ++j) {
      int c = q * 2 + j;
      vals[j] = *(const u16x8*)(hns + r * 256 + ((c ^ (r & 7)) << 4));
#pragma unroll
      for (int e = 0; e < 8; ++e) { float f = bf2f(vals[j][e]); sum += f * f; }
    }
    sum += __shfl_xor(sum, 1);
    sum += __shfl_xor(sum, 2);
    sum += __shfl_xor(sum, 4);
    float scale = rsqrtf(sum * (1.f / 128.f) + 1e-6f);
#pragma unroll
    for (int j = 0; j < 2; ++j) {
      u16x8 o;
#pragma unroll
      for (int e = 0; e < 8; ++e) o[e] = f2bf(bf2f(vals[j][e]) * scale);
      int c = q * 2 + j;
      *(u16x8*)(hns + r * 256 + ((c ^ (r & 7)) << 4)) = o;
    }
  }
  __syncthreads();

  // ---- GEMM1: h1 = sigmoid(hn @ W1 + b1) + hn -> h1s ----
  float b1v[2];
#pragma unroll
  for (int nt = 0; nt < 2; ++nt) b1v[nt] = bias[128 + n_base + nt * 16 + lane16];
  f32x4 acc1[2][2] = {};
#pragma unroll
  for (int kk = 0; kk < 4; ++kk) {
    int ph = ((kk * 4 + quad) ^ (lane & 7)) << 4;
    bf16x8 a[2], b[2];
#pragma unroll
    for (int rh = 0; rh < 2; ++rh)
      a[rh] = *(const bf16x8*)(hns + (m_base + rh * 16 + lane16) * 256 + ph);
#pragma unroll
    for (int nt = 0; nt < 2; ++nt)
      b[nt] = *(const bf16x8*)(w1t + (size_t)(n_base + nt * 16 + lane16) * 128 +
                               kk * 32 + quad * 8);
#pragma unroll
    for (int rh = 0; rh < 2; ++rh)
#pragma unroll
      for (int nt = 0; nt < 2; ++nt)
        acc1[rh][nt] = __builtin_amdgcn_mfma_f32_16x16x32_bf16(
            a[rh], b[nt], acc1[rh][nt], 0, 0, 0);
  }
#pragma unroll
  for (int rh = 0; rh < 2; ++rh)
#pragma unroll
    for (int nt = 0; nt < 2; ++nt) {
      int col = n_base + nt * 16 + lane16;
#pragma unroll
      for (int r = 0; r < 4; ++r) {
        int row = m_base + rh * 16 + quad * 4 + r;
        int o = hoff(row, col);
        float hn = bf2f(*(const u16*)(hns + o));
        float v = acc1[rh][nt][r] + b1v[nt];
        *(u16*)(h1s + o) = f2bf(hn + 1.f / (1.f + __expf(-v)));
      }
    }
  __syncthreads();

  // ---- GEMM2: out = relu(h1 @ W2 + b2) + h1, fused fp32 store ----
  float b2v[2];
#pragma unroll
  for (int nt = 0; nt < 2; ++nt) b2v[nt] = bias[256 + n_base + nt * 16 + lane16];
  f32x4 acc2[2][2] = {};
#pragma unroll
  for (int kk = 0; kk < 4; ++kk) {
    int ph = ((kk * 4 + quad) ^ (lane & 7)) << 4;
    bf16x8 a[2], b[2];
#pragma unroll
    for (int rh = 0; rh < 2; ++rh)
      a[rh] = *(const bf16x8*)(h1s + (m_base + rh * 16 + lane16) * 256 + ph);
#pragma unroll
    for (int nt = 0; nt < 2; ++nt)
      b[nt] = *(const bf16x8*)(w2t + (size_t)(n_base + nt * 16 + lane16) * 128 +
                               kk * 32 + quad * 8);
#pragma unroll
    for (int rh = 0; rh < 2; ++rh)
#pragma unroll
      for (int nt = 0; nt < 2; ++nt)
        acc2[rh][nt] = __builtin_amdgcn_mfma_f32_16x16x32_bf16(
            a[rh], b[nt], acc2[rh][nt], 0, 0, 0);
  }
#pragma unroll
  for (int rh = 0; rh < 2; ++rh)
#pragma unroll
    for (int nt = 0; nt < 2; ++nt) {
      int col = n_base + nt * 16 + lane16;
#pragma unroll
      for (int r = 0; r < 4; ++r) {
        int row = m_base + rh * 16 + quad * 4 + r;
        float h1v = bf2f(*(const u16*)(h1s + hoff(row, col)));
        float v = acc2[rh][nt][r] + b2v[nt];
        float res = h1v + fmaxf(v, 0.f);
        outv[(size_t)(row0 + row) * 128 + col] = res;
      }
    }
}

// ---------------------------------------------------------------------------
extern "C" void kernel_launch(void* const* d_in, const int* in_sizes, int n_in,
                              void* d_out, int out_size, void* d_ws, size_t ws_size,
                              hipStream_t stream) {
  const float* x  = (const float*)d_in[0];
  const float* W0 = (const float*)d_in[1];
  const float* b0 = (const float*)d_in[2];
  const float* W1 = (const float*)d_in[3];
  const float* b1 = (const float*)d_in[4];
  const float* W2 = (const float*)d_in[5];
  const float* b2 = (const float*)d_in[6];
  char* wsb = (char*)d_ws;

  prep_kernel<<<161, 256, 0, stream>>>(W0, W1, W2, b0, b1, b2, wsb);
  fused_kernel<<<512, 512, 0, stream>>>(x, wsb, (float*)d_out);
}